// Round 3
// baseline (3963.966 us; speedup 1.0000x reference)
//
#include <hip/hip_runtime.h>
#include <math.h>

#define D 128

// CK idiom: cast a global pointer into the constant address space so uniform
// reads compile to s_load_dwordx{4,8,16} (SGPR broadcast, scalar pipe).
#define CONSTP(p) ((__attribute__((address_space(4))) const float*)(size_t)(p))

__device__ __forceinline__ int lbound(const int* __restrict__ a, int L, int v) {
    int lo = 0, hi = L;
    while (lo < hi) { int m = (lo + hi) >> 1; if (a[m] < v) lo = m + 1; else hi = m; }
    return lo;
}

// Wave-level segmented atomic accumulate; all 64 lanes converged.
__device__ __forceinline__ void seg_atomic(float* __restrict__ seg, int g, float v, bool valid) {
    float tv = valid ? v : 0.f;
    float s = tv;
#pragma unroll
    for (int o = 1; o < 64; o <<= 1) s += __shfl_xor(s, o, 64);
    unsigned long long vb = __ballot(valid);
    if (vb == 0ULL) return;
    int g0 = __shfl(g, 0, 64);              // lane 0 valid whenever vb != 0 (valid = lane<K)
    unsigned long long ub = __ballot((!valid) || (g == g0));
    const int lane = (int)(threadIdx.x & 63u);
    if (ub == ~0ULL) {
        if (lane == 0) atomicAdd(seg + g0, s);
    } else {
        if (valid) atomicAdd(seg + g, tv);
    }
}

__device__ __forceinline__ void wave_add(float* __restrict__ dst, float v) {
    float s = v;
#pragma unroll
    for (int o = 1; o < 64; o <<= 1) s += __shfl_xor(s, o, 64);
    if ((threadIdx.x & 63u) == 0) atomicAdd(dst, s);
}

// Fused positive-edge kernel: attr head (W1,b1,W2,b2 -> loss_rec) + edge head
// (We1,be1,We2,be2 -> loss_edge_pos), one gather of em = relu(x[s]*x[d]).
// TILE = 64 edges; 8 waves; wave w owns W1 cols [16w,16w+16) and We1 cols same.
// k-loop: 1 ds_read_b32 (edge value, conflict-free) + 32 v_fmac with W in SGPRs.
__global__ __launch_bounds__(512, 4)
void pos_kernel(const float* __restrict__ x,
                const int*   __restrict__ ei, const int* __restrict__ ebatch,
                const float* __restrict__ W1,  const float* __restrict__ b1,
                const float* __restrict__ W2,  const float* __restrict__ b2,
                const float* __restrict__ We1, const float* __restrict__ be1,
                const float* __restrict__ We2, const float* __restrict__ be2,
                const float* __restrict__ attr,
                float* __restrict__ posSum, float* __restrict__ tot1,
                int E, int ntiles) {
    __shared__ float smem[16512];            // RT [128k][64e] = 8192 | H1/He 2x(64x129)
    const int t = (int)threadIdx.x;
    const int wv = t >> 6;
    const int lane = t & 63;
    const __attribute__((address_space(4))) const float* W1c  = CONSTP(W1)  + wv * 16;
    const __attribute__((address_space(4))) const float* We1c = CONSTP(We1) + wv * 16;

    for (int tile = (int)blockIdx.x; tile < ntiles; tile += (int)gridDim.x) {
        const int base = tile * 64;
        __syncthreads();                     // previous epilogue reads done
        // ---- gather: edge = lane, wave w stages k in [16w,16w+16)
        {
            const int Ei = base + lane;
            if (Ei < E) {
                const int s0 = ei[Ei], d0 = ei[E + Ei];
                const float4* xs = (const float4*)(x + (size_t)s0 * D + wv * 16);
                const float4* xd = (const float4*)(x + (size_t)d0 * D + wv * 16);
#pragma unroll
                for (int m = 0; m < 4; m++) {
                    float4 a = xs[m], b = xd[m];
                    const int k0 = wv * 16 + m * 4;
                    smem[(k0 + 0) * 64 + lane] = fmaxf(a.x * b.x, 0.f);
                    smem[(k0 + 1) * 64 + lane] = fmaxf(a.y * b.y, 0.f);
                    smem[(k0 + 2) * 64 + lane] = fmaxf(a.z * b.z, 0.f);
                    smem[(k0 + 3) * 64 + lane] = fmaxf(a.w * b.w, 0.f);
                }
            } else {
#pragma unroll
                for (int m = 0; m < 16; m++) smem[(wv * 16 + m) * 64 + lane] = 0.f;
            }
        }
        __syncthreads();

        // ---- k-loop
        float acc1[16], acc2[16];
#pragma unroll
        for (int i = 0; i < 16; i++) { acc1[i] = 0.f; acc2[i] = 0.f; }
#pragma unroll 2
        for (int k = 0; k < 128; k++) {
            const float r = smem[k * 64 + lane];
            const __attribute__((address_space(4))) const float* wa = W1c  + k * D;
            const __attribute__((address_space(4))) const float* wb = We1c + k * D;
#pragma unroll
            for (int i = 0; i < 16; i++) acc1[i] += r * wa[i];
#pragma unroll
            for (int i = 0; i < 16; i++) acc2[i] += r * wb[i];
        }

        __syncthreads();                     // all RT reads done before H overwrite
        // ---- H to LDS, stride 129 (conflict-free: bank = (e + j) % 32)
#pragma unroll
        for (int i = 0; i < 16; i++) {
            smem[lane * 129 + wv * 16 + i]        = acc1[i];
            smem[8256 + lane * 129 + wv * 16 + i] = acc2[i];
        }
        __syncthreads();

        // ---- second layer: 8 lanes per edge, chunk = 16 cols each
        const int er = lane & 7, ch = lane >> 3;
        const int e2 = wv * 8 + er;
        float s[7] = {0.f, 0.f, 0.f, 0.f, 0.f, 0.f, 0.f};
        float sp = 0.f;
#pragma unroll 4
        for (int i = 0; i < 16; i++) {
            const int j = ch * 16 + i;
            const float h1 = fmaxf(smem[e2 * 129 + j] + b1[j], 0.f);
            const float he = fmaxf(smem[8256 + e2 * 129 + j] + be1[j], 0.f);
#pragma unroll
            for (int c = 0; c < 7; c++) s[c] += h1 * W2[j * 7 + c];
            sp += he * We2[j];
        }
#pragma unroll
        for (int o = 8; o < 64; o <<= 1) {
#pragma unroll
            for (int c = 0; c < 7; c++) s[c] += __shfl_xor(s[c], o, 64);
            sp += __shfl_xor(sp, o, 64);
        }
        const int Ei = base + e2;
        const bool valid = (lane < 8) && (Ei < E);
        float lossTot = 0.f, lossP = 0.f;
        int g = 0;
        if (valid) {
#pragma unroll
            for (int c = 0; c < 7; c++) {
                const float z = s[c] + b2[c];
                const float p = 1.f / (1.f + expf(-z));
                const float ta = attr[(size_t)Ei * 9 + c];
                const float lp = fmaxf(logf(p), -100.f);
                const float ln = fmaxf(log1pf(-p), -100.f);
                lossTot -= ta * lp + (1.f - ta) * ln;
            }
            const float zp = sp + be2[0];
            const float pp = 1.f / (1.f + expf(-zp));
            lossP = -fmaxf(logf(pp), -100.f);
            lossTot += lossP;
            g = ebatch[Ei];
        }
        seg_atomic(posSum, g, lossTot, valid);
        wave_add(tot1, valid ? lossP : 0.f);
    }
}

// Negative-edge kernel: edge head only. TILE = 128 edges; waves 0-3 edges 0-63,
// waves 4-7 edges 64-127; col slice = 32 per wave.
__global__ __launch_bounds__(512, 4)
void neg_kernel(const float* __restrict__ x,
                const int*   __restrict__ ei, const int* __restrict__ ebatch,
                const float* __restrict__ We1, const float* __restrict__ be1,
                const float* __restrict__ We2, const float* __restrict__ be2,
                float* __restrict__ negSum, float* __restrict__ tot2,
                int E, int ntiles) {
    __shared__ float smem[16512];            // RT [128k][128e] = 16384 | H 128x129
    const int t = (int)threadIdx.x;
    const int wv = t >> 6;
    const int lane = t & 63;
    const int eb = (wv >> 2) << 6;           // edge-half base (0 or 64)
    const int j0 = (wv & 3) * 32;            // col slice
    const __attribute__((address_space(4))) const float* Wc = CONSTP(We1) + j0;

    for (int tile = (int)blockIdx.x; tile < ntiles; tile += (int)gridDim.x) {
        const int base = tile * 128;
        __syncthreads();
        // ---- gather: e = t&127, quarter kq = t>>7 covers 32 k's
        {
            const int e = t & 127, kq = t >> 7;
            const int Ei = base + e;
            if (Ei < E) {
                const int s0 = ei[Ei], d0 = ei[E + Ei];
                const float4* xs = (const float4*)(x + (size_t)s0 * D + kq * 32);
                const float4* xd = (const float4*)(x + (size_t)d0 * D + kq * 32);
#pragma unroll
                for (int m = 0; m < 8; m++) {
                    float4 a = xs[m], b = xd[m];
                    const int k0 = kq * 32 + m * 4;
                    smem[(k0 + 0) * 128 + e] = fmaxf(a.x * b.x, 0.f);
                    smem[(k0 + 1) * 128 + e] = fmaxf(a.y * b.y, 0.f);
                    smem[(k0 + 2) * 128 + e] = fmaxf(a.z * b.z, 0.f);
                    smem[(k0 + 3) * 128 + e] = fmaxf(a.w * b.w, 0.f);
                }
            } else {
#pragma unroll
                for (int m = 0; m < 32; m++) smem[(kq * 32 + m) * 128 + e] = 0.f;
            }
        }
        __syncthreads();

        float acc[32];
#pragma unroll
        for (int i = 0; i < 32; i++) acc[i] = 0.f;
#pragma unroll 2
        for (int k = 0; k < 128; k++) {
            const float r = smem[k * 128 + eb + lane];
            const __attribute__((address_space(4))) const float* w = Wc + k * D;
#pragma unroll
            for (int i = 0; i < 32; i++) acc[i] += r * w[i];
        }

        __syncthreads();
        const int eg = eb + lane;
#pragma unroll
        for (int i = 0; i < 32; i++) smem[eg * 129 + j0 + i] = acc[i];
        __syncthreads();

        // ---- second layer: 4 lanes per edge, 32 cols each
        const int er = lane & 15, ch = lane >> 4;
        const int e2 = wv * 16 + er;
        float sp = 0.f;
#pragma unroll 8
        for (int i = 0; i < 32; i++) {
            const int j = ch * 32 + i;
            const float he = fmaxf(smem[e2 * 129 + j] + be1[j], 0.f);
            sp += he * We2[j];
        }
        sp += __shfl_xor(sp, 16, 64);
        sp += __shfl_xor(sp, 32, 64);
        const int Ei = base + e2;
        const bool valid = (lane < 16) && (Ei < E);
        float lossN = 0.f;
        int g = 0;
        if (valid) {
            const float zp = sp + be2[0];
            const float pp = 1.f / (1.f + expf(-zp));
            lossN = -fmaxf(log1pf(-pp), -100.f);
            g = ebatch[Ei];
        }
        seg_atomic(negSum, g, lossN, valid);
        wave_add(tot2, valid ? lossN : 0.f);
    }
}

__global__ __launch_bounds__(256)
void kl_kernel(const float* __restrict__ xm, const float* __restrict__ xs,
               const int* __restrict__ batch, float* __restrict__ klSum, int N) {
    const int n = (int)(blockIdx.x * 256 + threadIdx.x);
    const bool valid = (n < N);
    float kl = 0.f;
    int g = 0;
    if (valid) {
        const float4* m4 = (const float4*)(xm + (size_t)n * D);
        const float4* s4 = (const float4*)(xs + (size_t)n * D);
        float s = 0.f;
        // Clamp log at -1e4 (< log(min denormal)): bit-identical for sd > 0,
        // finite at sd == 0 where the reference is +inf (threshold inf).
#pragma unroll 8
        for (int i = 0; i < 32; i++) {
            const float4 m = m4[i];
            const float4 sd = s4[i];
            s += 1.f + 2.f * fmaxf(logf(sd.x), -1e4f) - m.x * m.x - sd.x * sd.x;
            s += 1.f + 2.f * fmaxf(logf(sd.y), -1e4f) - m.y * m.y - sd.y * sd.y;
            s += 1.f + 2.f * fmaxf(logf(sd.z), -1e4f) - m.z * m.z - sd.z * sd.z;
            s += 1.f + 2.f * fmaxf(logf(sd.w), -1e4f) - m.w * m.w - sd.w * sd.w;
        }
        kl = -0.5f * s;
        g = batch[n];
    }
    seg_atomic(klSum, g, kl, valid);
}

__global__ __launch_bounds__(256)
void final_kernel(const int* __restrict__ eib, const int* __restrict__ einb,
                  const int* __restrict__ nbatch,
                  const float* __restrict__ posSum, const float* __restrict__ negSum,
                  const float* __restrict__ klSum,
                  float* __restrict__ tot, int E, int N, int G) {
    const int g = (int)(blockIdx.x * blockDim.x + threadIdx.x);
    float lg = 0.f;
    if (g < G) {
        const int cP = lbound(eib, E, g + 1) - lbound(eib, E, g);
        const int cN = lbound(einb, E, g + 1) - lbound(einb, E, g);
        const int cB = lbound(nbatch, N, g + 1) - lbound(nbatch, N, g);
        const float fp = fmaxf((float)cP, 1.f);
        const float fn = fmaxf((float)cN, 1.f);
        const float fb = fmaxf((float)cB, 1.f);
        lg = posSum[g] / fp + negSum[g] / fn + (klSum[g] / fb) / fb;
    }
#pragma unroll
    for (int o = 1; o < 64; o <<= 1) lg += __shfl_xor(lg, o, 64);
    if ((threadIdx.x & 63u) == 0) atomicAdd(tot, lg);
}

__global__ void out_kernel(const float* __restrict__ tot, float* __restrict__ out,
                           int E, int G) {
    if (threadIdx.x == 0 && blockIdx.x == 0) {
        out[0] = tot[0] / (float)G;
        out[1] = 0.5f * (tot[1] / (float)E + tot[2] / (float)E);
    }
}

extern "C" void kernel_launch(void* const* d_in, const int* in_sizes, int n_in,
                              void* d_out, int out_size, void* d_ws, size_t ws_size,
                              hipStream_t stream) {
    const float* x    = (const float*)d_in[0];
    const float* attr = (const float*)d_in[1];
    const float* xm   = (const float*)d_in[2];
    const float* xsd  = (const float*)d_in[3];
    const float* W1   = (const float*)d_in[4];
    const float* b1   = (const float*)d_in[5];
    const float* W2   = (const float*)d_in[6];
    const float* b2   = (const float*)d_in[7];
    const float* We1  = (const float*)d_in[8];
    const float* be1  = (const float*)d_in[9];
    const float* We2  = (const float*)d_in[10];
    const float* be2  = (const float*)d_in[11];
    const int* ei     = (const int*)d_in[12];
    const int* ein    = (const int*)d_in[13];
    const int* eib    = (const int*)d_in[14];
    const int* einb   = (const int*)d_in[15];
    const int* batch  = (const int*)d_in[16];

    const int N = in_sizes[0] / D;       // 100000
    const int E = in_sizes[14];          // 600000
    const int G = 1024;

    float* ws = (float*)d_ws;
    float* posSum = ws;                  // [G]
    float* negSum = ws + G;              // [G]
    float* klSum  = ws + 2 * G;          // [G]
    float* tot    = ws + 3 * G;          // [0]=loss, [1]=sum lep, [2]=sum len

    hipMemsetAsync(d_ws, 0, (size_t)(3 * G + 3) * sizeof(float), stream);

    const int ntA = (E + 63) / 64;
    const int ntB = (E + 127) / 128;
    const int gA = ntA < 512 ? ntA : 512;
    const int gB = ntB < 512 ? ntB : 512;

    pos_kernel<<<gA, 512, 0, stream>>>(x, ei, eib, W1, b1, W2, b2,
                                       We1, be1, We2, be2, attr,
                                       posSum, tot + 1, E, ntA);
    neg_kernel<<<gB, 512, 0, stream>>>(x, ein, einb, We1, be1, We2, be2,
                                       negSum, tot + 2, E, ntB);
    kl_kernel<<<(N + 255) / 256, 256, 0, stream>>>(xm, xsd, batch, klSum, N);
    final_kernel<<<(G + 255) / 256, 256, 0, stream>>>(eib, einb, batch,
                                                      posSum, negSum, klSum, tot, E, N, G);
    out_kernel<<<1, 64, 0, stream>>>(tot, (float*)d_out, E, G);
}

// Round 4
// 975.081 us; speedup vs baseline: 4.0653x; 4.0653x over previous
//
#include <hip/hip_runtime.h>
#include <math.h>

#define D 128

typedef __bf16 bf16x8 __attribute__((ext_vector_type(8)));
typedef float f32x4 __attribute__((ext_vector_type(4)));

__device__ __forceinline__ unsigned short f2bf(float f) {
    unsigned u = __float_as_uint(f);
    return (unsigned short)((u + 0x7FFFu + ((u >> 16) & 1u)) >> 16);
}
__device__ __forceinline__ float bf2f(unsigned short h) {
    return __uint_as_float(((unsigned)h) << 16);
}

__device__ __forceinline__ int lbound(const int* __restrict__ a, int L, int v) {
    int lo = 0, hi = L;
    while (lo < hi) { int m = (lo + hi) >> 1; if (a[m] < v) lo = m + 1; else hi = m; }
    return lo;
}

// Wave-level segmented atomic accumulate; all 64 lanes of the wave converged.
__device__ __forceinline__ void seg_atomic(float* __restrict__ seg, int g, float v, bool valid) {
    float tv = valid ? v : 0.f;
    float s = tv;
#pragma unroll
    for (int o = 1; o < 64; o <<= 1) s += __shfl_xor(s, o, 64);
    unsigned long long vb = __ballot(valid);
    if (vb == 0ULL) return;
    int g0 = __shfl(g, __ffsll((unsigned long long)vb) - 1, 64);
    unsigned long long ub = __ballot((!valid) || (g == g0));
    const int lane = (int)(threadIdx.x & 63u);
    if (ub == ~0ULL) {
        if (lane == 0) atomicAdd(seg + g0, s);
    } else {
        if (valid) atomicAdd(seg + g, tv);
    }
}

__device__ __forceinline__ void wave_add(float* __restrict__ dst, float v) {
    float s = v;
#pragma unroll
    for (int o = 1; o < 64; o <<= 1) s += __shfl_xor(s, o, 64);
    if ((threadIdx.x & 63u) == 0) atomicAdd(dst, s);
}

// A-fragment LDS layout (16x16x32 MFMA): slot(mt,kt,quad,m) = ((mt*4+kt)*64 + quad*16 + m),
// 16 B per slot; reader lane l uses slot ((mt*4+kt)*64 + l) -> linear, conflict-free.

// Positive-edge kernel: both heads, M=64 edges/tile, 8 waves.
// Waves 0-3: W1-head cols 32w..32w+32 (plain bf16).  Waves 4-7: We1-head (hi+lo bf16).
__global__ __launch_bounds__(512, 4)
void pos_kernel(const float* __restrict__ x,
                const int* __restrict__ ei, const int* __restrict__ ebatch,
                const float* __restrict__ W1, const float* __restrict__ b1,
                const float* __restrict__ W2, const float* __restrict__ b2,
                const float* __restrict__ We1, const float* __restrict__ be1,
                const float* __restrict__ We2, const float* __restrict__ be2,
                const float* __restrict__ attr,
                float* __restrict__ posSum, float* __restrict__ tot1,
                int E, int ntiles) {
    __shared__ float smem[9104];
    unsigned short* As  = (unsigned short*)smem;            // 1024 slots x 16 B (16 KB)
    unsigned short* Hbf = (unsigned short*)(smem + 4096);   // H1 relu'd: [64][136] bf16
    float* posP = smem + 8448;                              // [4][64] We-head partials
    float* b1s  = smem + 8704;
    float* be1s = smem + 8832;
    float* We2s = smem + 8960;
    float* b2s  = smem + 9088;                              // 7 (+1)
    float* be2s = smem + 9096;

    const int t   = (int)threadIdx.x;
    const int wv  = t >> 6;
    const int l   = t & 63;
    const int sub = l & 15;
    const int q   = l >> 4;

    bf16x8 Bh[2][4];   // wv<4: W1 cols; wv>=4: We1-hi cols
    bf16x8 Bl[2][4];   // wv>=4: We1-lo; wv<4: Bl[0][kt] = W2 fragment (layer-2 GEMM)

    // ---- one-time B staging: 12 passes through the A region
#pragma unroll
    for (int pass = 0; pass < 12; pass++) {
        const int mm = (pass < 4) ? 0 : 1;
        const int p  = (pass < 8) ? 0 : 1;
        const int kt = pass & 3;
        const float* Wsrc = mm ? We1 : W1;
        __syncthreads();
        {
            const int ct = t >> 6, ln = t & 63;
            const int n  = ct * 16 + (ln & 15);
            const int kb = kt * 32 + (ln >> 4) * 8;
            unsigned v[4];
#pragma unroll
            for (int jj = 0; jj < 4; jj++) {
                float f0 = Wsrc[(kb + 2 * jj) * D + n];
                float f1 = Wsrc[(kb + 2 * jj + 1) * D + n];
                unsigned short h0, h1;
                if (p == 0) { h0 = f2bf(f0); h1 = f2bf(f1); }
                else {
                    h0 = f2bf(f0 - bf2f(f2bf(f0)));
                    h1 = f2bf(f1 - bf2f(f2bf(f1)));
                }
                v[jj] = (unsigned)h0 | ((unsigned)h1 << 16);
            }
            uint4 u; u.x = v[0]; u.y = v[1]; u.z = v[2]; u.w = v[3];
            *(uint4*)(As + (ct * 64 + ln) * 8) = u;
        }
        __syncthreads();
        int ct0 = -1;
        if (mm == 0 && wv < 4)  ct0 = 2 * wv;
        if (mm == 1 && wv >= 4) ct0 = 2 * (wv - 4);
        if (ct0 >= 0) {
            bf16x8 f0 = *(const bf16x8*)(As + (ct0 * 64 + l) * 8);
            bf16x8 f1 = *(const bf16x8*)(As + ((ct0 + 1) * 64 + l) * 8);
            if (p == 0) { Bh[0][kt] = f0; Bh[1][kt] = f1; }
            else        { Bl[0][kt] = f0; Bl[1][kt] = f1; }
        }
    }
    // wv<4: W2 fragments (B-operand of the 64x16x128 layer-2 GEMM), cols 7..15 zero
    if (wv < 4) {
#pragma unroll
        for (int kt = 0; kt < 4; kt++) {
            const int kb = kt * 32 + q * 8;
            unsigned v[4];
#pragma unroll
            for (int jj = 0; jj < 4; jj++) {
                unsigned short h0 = (sub < 7) ? f2bf(W2[(kb + 2 * jj) * 7 + sub]) : (unsigned short)0;
                unsigned short h1 = (sub < 7) ? f2bf(W2[(kb + 2 * jj + 1) * 7 + sub]) : (unsigned short)0;
                v[jj] = (unsigned)h0 | ((unsigned)h1 << 16);
            }
            union { uint4 u; bf16x8 b; } cv;
            cv.u.x = v[0]; cv.u.y = v[1]; cv.u.z = v[2]; cv.u.w = v[3];
            Bl[0][kt] = cv.b;
        }
    }
    __syncthreads();
    if (t < 128) { b1s[t] = b1[t]; be1s[t] = be1[t]; We2s[t] = We2[t]; }
    if (t < 7) b2s[t] = b2[t];
    if (t == 7) be2s[0] = be2[0];

    for (int tile = (int)blockIdx.x; tile < ntiles; tile += (int)gridDim.x) {
        const int base = tile * 64;
        __syncthreads();
        // ---- gather em = relu(x[s]*x[d]) -> bf16 -> swizzled A frags
        {
            const int e = t >> 3, ks = t & 7;
            const int Ei = base + e, k0 = ks * 16;
            unsigned v[8];
            if (Ei < E) {
                const int s0 = ei[Ei], d0 = ei[E + Ei];
                const float4* ps = (const float4*)(x + (size_t)s0 * D + k0);
                const float4* pd = (const float4*)(x + (size_t)d0 * D + k0);
#pragma unroll
                for (int i2 = 0; i2 < 4; i2++) {
                    float4 a = ps[i2], b = pd[i2];
                    unsigned short p0 = f2bf(fmaxf(a.x * b.x, 0.f));
                    unsigned short p1 = f2bf(fmaxf(a.y * b.y, 0.f));
                    unsigned short p2 = f2bf(fmaxf(a.z * b.z, 0.f));
                    unsigned short p3 = f2bf(fmaxf(a.w * b.w, 0.f));
                    v[i2 * 2]     = (unsigned)p0 | ((unsigned)p1 << 16);
                    v[i2 * 2 + 1] = (unsigned)p2 | ((unsigned)p3 << 16);
                }
            } else {
#pragma unroll
                for (int i2 = 0; i2 < 8; i2++) v[i2] = 0u;
            }
            const int slot = ((e >> 4) * 4 + (ks >> 1)) * 64 + (ks & 1) * 32 + (e & 15);
            uint4 u0; u0.x = v[0]; u0.y = v[1]; u0.z = v[2]; u0.w = v[3];
            uint4 u1; u1.x = v[4]; u1.y = v[5]; u1.z = v[6]; u1.w = v[7];
            *(uint4*)(As + slot * 8) = u0;
            *(uint4*)(As + (slot + 16) * 8) = u1;
        }
        __syncthreads();
        // ---- layer-1 MFMAs + per-wave epilogue
#pragma unroll
        for (int mt = 0; mt < 4; mt++) {
            bf16x8 a0 = *(const bf16x8*)(As + ((mt * 4 + 0) * 64 + l) * 8);
            bf16x8 a1 = *(const bf16x8*)(As + ((mt * 4 + 1) * 64 + l) * 8);
            bf16x8 a2 = *(const bf16x8*)(As + ((mt * 4 + 2) * 64 + l) * 8);
            bf16x8 a3 = *(const bf16x8*)(As + ((mt * 4 + 3) * 64 + l) * 8);
            float zp0 = 0.f, zp1 = 0.f, zp2 = 0.f, zp3 = 0.f;
#pragma unroll
            for (int ct = 0; ct < 2; ct++) {
                f32x4 c = {0.f, 0.f, 0.f, 0.f};
                c = __builtin_amdgcn_mfma_f32_16x16x32_bf16(a0, Bh[ct][0], c, 0, 0, 0);
                c = __builtin_amdgcn_mfma_f32_16x16x32_bf16(a1, Bh[ct][1], c, 0, 0, 0);
                c = __builtin_amdgcn_mfma_f32_16x16x32_bf16(a2, Bh[ct][2], c, 0, 0, 0);
                c = __builtin_amdgcn_mfma_f32_16x16x32_bf16(a3, Bh[ct][3], c, 0, 0, 0);
                if (wv >= 4) {
                    c = __builtin_amdgcn_mfma_f32_16x16x32_bf16(a0, Bl[ct][0], c, 0, 0, 0);
                    c = __builtin_amdgcn_mfma_f32_16x16x32_bf16(a1, Bl[ct][1], c, 0, 0, 0);
                    c = __builtin_amdgcn_mfma_f32_16x16x32_bf16(a2, Bl[ct][2], c, 0, 0, 0);
                    c = __builtin_amdgcn_mfma_f32_16x16x32_bf16(a3, Bl[ct][3], c, 0, 0, 0);
                }
                const int jloc = (wv & 3) * 32 + ct * 16 + sub;
                if (wv < 4) {
                    const float bb = b1s[jloc];
#pragma unroll
                    for (int r = 0; r < 4; r++)
                        Hbf[(mt * 16 + q * 4 + r) * 136 + jloc] = f2bf(fmaxf(c[r] + bb, 0.f));
                } else {
                    const float bb = be1s[jloc], ww = We2s[jloc];
                    zp0 += fmaxf(c[0] + bb, 0.f) * ww;
                    zp1 += fmaxf(c[1] + bb, 0.f) * ww;
                    zp2 += fmaxf(c[2] + bb, 0.f) * ww;
                    zp3 += fmaxf(c[3] + bb, 0.f) * ww;
                }
            }
            if (wv >= 4) {
#pragma unroll
                for (int o = 1; o < 16; o <<= 1) {
                    zp0 += __shfl_xor(zp0, o, 64);
                    zp1 += __shfl_xor(zp1, o, 64);
                    zp2 += __shfl_xor(zp2, o, 64);
                    zp3 += __shfl_xor(zp3, o, 64);
                }
                if (sub < 4) {
                    float vv = (sub == 0) ? zp0 : (sub == 1) ? zp1 : (sub == 2) ? zp2 : zp3;
                    posP[(wv - 4) * 64 + mt * 16 + q * 4 + sub] = vv;
                }
            }
        }
        __syncthreads();
        // ---- layer 2 (waves 0-3): S = Hbf @ W2frag via MFMA; lane sub==7 does We-head
        if (wv < 4) {
            f32x4 cS = {0.f, 0.f, 0.f, 0.f};
#pragma unroll
            for (int jt = 0; jt < 4; jt++) {
                bf16x8 hf = *(const bf16x8*)(Hbf + (wv * 16 + sub) * 136 + jt * 32 + q * 8);
                cS = __builtin_amdgcn_mfma_f32_16x16x32_bf16(hf, Bl[0][jt], cS, 0, 0, 0);
            }
            float bceP[4] = {0.f, 0.f, 0.f, 0.f};
            float lpP[4]  = {0.f, 0.f, 0.f, 0.f};
#pragma unroll
            for (int r = 0; r < 4; r++) {
                const int e = wv * 16 + q * 4 + r;
                const int Ei = base + e;
                const bool vE = (Ei < E);
                if (sub < 7 && vE) {
                    const float z = cS[r] + b2s[sub];
                    const float p = 1.f / (1.f + expf(-z));
                    const float ta = attr[(size_t)Ei * 9 + sub];
                    bceP[r] = -(ta * fmaxf(logf(p), -100.f)
                              + (1.f - ta) * fmaxf(log1pf(-p), -100.f));
                } else if (sub == 7 && vE) {
                    const float zp = posP[e] + posP[64 + e] + posP[128 + e] + posP[192 + e] + be2s[0];
                    const float pp = 1.f / (1.f + expf(-zp));
                    lpP[r]  = -fmaxf(logf(pp), -100.f);
                    bceP[r] = lpP[r];
                }
            }
#pragma unroll
            for (int o = 1; o < 16; o <<= 1)
#pragma unroll
                for (int r = 0; r < 4; r++) {
                    bceP[r] += __shfl_xor(bceP[r], o, 64);
                    lpP[r]  += __shfl_xor(lpP[r],  o, 64);
                }
            const float lossSel = (sub == 0) ? bceP[0] : (sub == 1) ? bceP[1]
                                : (sub == 2) ? bceP[2] : bceP[3];
            const float lpSel   = (sub == 0) ? lpP[0] : (sub == 1) ? lpP[1]
                                : (sub == 2) ? lpP[2] : lpP[3];
            const int eW  = wv * 16 + q * 4 + (sub & 3);
            const int EiW = base + eW;
            const bool act = (sub < 4) && (EiW < E);
            const int g = ebatch[EiW < E ? EiW : E - 1];
            seg_atomic(posSum, g, lossSel, act);
            wave_add(tot1, act ? lpSel : 0.f);
        }
    }
}

// Negative-edge kernel: We-head only. M=64, 8 waves x 16 cols, We1 hi+lo.
__global__ __launch_bounds__(512, 4)
void neg_kernel(const float* __restrict__ x,
                const int* __restrict__ ei, const int* __restrict__ ebatch,
                const float* __restrict__ We1, const float* __restrict__ be1,
                const float* __restrict__ We2, const float* __restrict__ be2,
                float* __restrict__ negSum, float* __restrict__ tot2,
                int E, int ntiles) {
    __shared__ float smem[4872];
    unsigned short* As = (unsigned short*)smem;     // 16 KB A frags
    float* negP = smem + 4096;                      // [8][64]
    float* be1s = smem + 4608;
    float* We2s = smem + 4736;
    float* be2s = smem + 4864;

    const int t   = (int)threadIdx.x;
    const int wv  = t >> 6;
    const int l   = t & 63;
    const int sub = l & 15;
    const int q   = l >> 4;

    bf16x8 Bh[4], Bl[4];
#pragma unroll
    for (int pass = 0; pass < 8; pass++) {
        const int p  = pass >> 2;
        const int kt = pass & 3;
        __syncthreads();
        {
            const int ct = t >> 6, ln = t & 63;
            const int n  = ct * 16 + (ln & 15);
            const int kb = kt * 32 + (ln >> 4) * 8;
            unsigned v[4];
#pragma unroll
            for (int jj = 0; jj < 4; jj++) {
                float f0 = We1[(kb + 2 * jj) * D + n];
                float f1 = We1[(kb + 2 * jj + 1) * D + n];
                unsigned short h0, h1;
                if (p == 0) { h0 = f2bf(f0); h1 = f2bf(f1); }
                else {
                    h0 = f2bf(f0 - bf2f(f2bf(f0)));
                    h1 = f2bf(f1 - bf2f(f2bf(f1)));
                }
                v[jj] = (unsigned)h0 | ((unsigned)h1 << 16);
            }
            uint4 u; u.x = v[0]; u.y = v[1]; u.z = v[2]; u.w = v[3];
            *(uint4*)(As + (ct * 64 + ln) * 8) = u;
        }
        __syncthreads();
        {
            bf16x8 f0 = *(const bf16x8*)(As + (wv * 64 + l) * 8);
            if (p == 0) Bh[kt] = f0; else Bl[kt] = f0;
        }
    }
    __syncthreads();
    if (t < 128) { be1s[t] = be1[t]; We2s[t] = We2[t]; }
    if (t == 128) be2s[0] = be2[0];

    for (int tile = (int)blockIdx.x; tile < ntiles; tile += (int)gridDim.x) {
        const int base = tile * 64;
        __syncthreads();
        {
            const int e = t >> 3, ks = t & 7;
            const int Ei = base + e, k0 = ks * 16;
            unsigned v[8];
            if (Ei < E) {
                const int s0 = ei[Ei], d0 = ei[E + Ei];
                const float4* ps = (const float4*)(x + (size_t)s0 * D + k0);
                const float4* pd = (const float4*)(x + (size_t)d0 * D + k0);
#pragma unroll
                for (int i2 = 0; i2 < 4; i2++) {
                    float4 a = ps[i2], b = pd[i2];
                    unsigned short p0 = f2bf(fmaxf(a.x * b.x, 0.f));
                    unsigned short p1 = f2bf(fmaxf(a.y * b.y, 0.f));
                    unsigned short p2 = f2bf(fmaxf(a.z * b.z, 0.f));
                    unsigned short p3 = f2bf(fmaxf(a.w * b.w, 0.f));
                    v[i2 * 2]     = (unsigned)p0 | ((unsigned)p1 << 16);
                    v[i2 * 2 + 1] = (unsigned)p2 | ((unsigned)p3 << 16);
                }
            } else {
#pragma unroll
                for (int i2 = 0; i2 < 8; i2++) v[i2] = 0u;
            }
            const int slot = ((e >> 4) * 4 + (ks >> 1)) * 64 + (ks & 1) * 32 + (e & 15);
            uint4 u0; u0.x = v[0]; u0.y = v[1]; u0.z = v[2]; u0.w = v[3];
            uint4 u1; u1.x = v[4]; u1.y = v[5]; u1.z = v[6]; u1.w = v[7];
            *(uint4*)(As + slot * 8) = u0;
            *(uint4*)(As + (slot + 16) * 8) = u1;
        }
        __syncthreads();
        const int j = wv * 16 + sub;
        const float bb = be1s[j], ww = We2s[j];
#pragma unroll
        for (int mt = 0; mt < 4; mt++) {
            bf16x8 a0 = *(const bf16x8*)(As + ((mt * 4 + 0) * 64 + l) * 8);
            bf16x8 a1 = *(const bf16x8*)(As + ((mt * 4 + 1) * 64 + l) * 8);
            bf16x8 a2 = *(const bf16x8*)(As + ((mt * 4 + 2) * 64 + l) * 8);
            bf16x8 a3 = *(const bf16x8*)(As + ((mt * 4 + 3) * 64 + l) * 8);
            f32x4 c = {0.f, 0.f, 0.f, 0.f};
            c = __builtin_amdgcn_mfma_f32_16x16x32_bf16(a0, Bh[0], c, 0, 0, 0);
            c = __builtin_amdgcn_mfma_f32_16x16x32_bf16(a1, Bh[1], c, 0, 0, 0);
            c = __builtin_amdgcn_mfma_f32_16x16x32_bf16(a2, Bh[2], c, 0, 0, 0);
            c = __builtin_amdgcn_mfma_f32_16x16x32_bf16(a3, Bh[3], c, 0, 0, 0);
            c = __builtin_amdgcn_mfma_f32_16x16x32_bf16(a0, Bl[0], c, 0, 0, 0);
            c = __builtin_amdgcn_mfma_f32_16x16x32_bf16(a1, Bl[1], c, 0, 0, 0);
            c = __builtin_amdgcn_mfma_f32_16x16x32_bf16(a2, Bl[2], c, 0, 0, 0);
            c = __builtin_amdgcn_mfma_f32_16x16x32_bf16(a3, Bl[3], c, 0, 0, 0);
            float zp0 = fmaxf(c[0] + bb, 0.f) * ww;
            float zp1 = fmaxf(c[1] + bb, 0.f) * ww;
            float zp2 = fmaxf(c[2] + bb, 0.f) * ww;
            float zp3 = fmaxf(c[3] + bb, 0.f) * ww;
#pragma unroll
            for (int o = 1; o < 16; o <<= 1) {
                zp0 += __shfl_xor(zp0, o, 64);
                zp1 += __shfl_xor(zp1, o, 64);
                zp2 += __shfl_xor(zp2, o, 64);
                zp3 += __shfl_xor(zp3, o, 64);
            }
            if (sub < 4) {
                float vv = (sub == 0) ? zp0 : (sub == 1) ? zp1 : (sub == 2) ? zp2 : zp3;
                negP[wv * 64 + mt * 16 + q * 4 + sub] = vv;
            }
        }
        __syncthreads();
        if (wv == 0) {
            const int Ei = base + l;
            const bool valid = (Ei < E);
            float zp = be2s[0];
#pragma unroll
            for (int i = 0; i < 8; i++) zp += negP[i * 64 + l];
            float lossN = 0.f;
            if (valid) {
                const float pp = 1.f / (1.f + expf(-zp));
                lossN = -fmaxf(log1pf(-pp), -100.f);
            }
            const int g = ebatch[Ei < E ? Ei : E - 1];
            seg_atomic(negSum, g, lossN, valid);
            wave_add(tot2, valid ? lossN : 0.f);
        }
    }
}

__global__ __launch_bounds__(256)
void kl_kernel(const float* __restrict__ xm, const float* __restrict__ xs,
               const int* __restrict__ batch, float* __restrict__ klSum, int N) {
    const int n = (int)(blockIdx.x * 256 + threadIdx.x);
    const bool valid = (n < N);
    float kl = 0.f;
    int g = 0;
    if (valid) {
        const float4* m4 = (const float4*)(xm + (size_t)n * D);
        const float4* s4 = (const float4*)(xs + (size_t)n * D);
        float s = 0.f;
        // Clamp log at -1e4 (< log(min denormal)): bit-identical for sd > 0,
        // finite at sd == 0 where the reference is +inf (threshold inf).
#pragma unroll 8
        for (int i = 0; i < 32; i++) {
            const float4 m = m4[i];
            const float4 sd = s4[i];
            s += 1.f + 2.f * fmaxf(logf(sd.x), -1e4f) - m.x * m.x - sd.x * sd.x;
            s += 1.f + 2.f * fmaxf(logf(sd.y), -1e4f) - m.y * m.y - sd.y * sd.y;
            s += 1.f + 2.f * fmaxf(logf(sd.z), -1e4f) - m.z * m.z - sd.z * sd.z;
            s += 1.f + 2.f * fmaxf(logf(sd.w), -1e4f) - m.w * m.w - sd.w * sd.w;
        }
        kl = -0.5f * s;
        g = batch[n];
    }
    seg_atomic(klSum, g, kl, valid);
}

__global__ __launch_bounds__(256)
void final_kernel(const int* __restrict__ eib, const int* __restrict__ einb,
                  const int* __restrict__ nbatch,
                  const float* __restrict__ posSum, const float* __restrict__ negSum,
                  const float* __restrict__ klSum,
                  float* __restrict__ tot, int E, int N, int G) {
    const int g = (int)(blockIdx.x * blockDim.x + threadIdx.x);
    float lg = 0.f;
    if (g < G) {
        const int cP = lbound(eib, E, g + 1) - lbound(eib, E, g);
        const int cN = lbound(einb, E, g + 1) - lbound(einb, E, g);
        const int cB = lbound(nbatch, N, g + 1) - lbound(nbatch, N, g);
        const float fp = fmaxf((float)cP, 1.f);
        const float fn = fmaxf((float)cN, 1.f);
        const float fb = fmaxf((float)cB, 1.f);
        lg = posSum[g] / fp + negSum[g] / fn + (klSum[g] / fb) / fb;
    }
#pragma unroll
    for (int o = 1; o < 64; o <<= 1) lg += __shfl_xor(lg, o, 64);
    if ((threadIdx.x & 63u) == 0) atomicAdd(tot, lg);
}

__global__ void out_kernel(const float* __restrict__ tot, float* __restrict__ out,
                           int E, int G) {
    if (threadIdx.x == 0 && blockIdx.x == 0) {
        out[0] = tot[0] / (float)G;
        out[1] = 0.5f * (tot[1] / (float)E + tot[2] / (float)E);
    }
}

extern "C" void kernel_launch(void* const* d_in, const int* in_sizes, int n_in,
                              void* d_out, int out_size, void* d_ws, size_t ws_size,
                              hipStream_t stream) {
    const float* x    = (const float*)d_in[0];
    const float* attr = (const float*)d_in[1];
    const float* xm   = (const float*)d_in[2];
    const float* xsd  = (const float*)d_in[3];
    const float* W1   = (const float*)d_in[4];
    const float* b1   = (const float*)d_in[5];
    const float* W2   = (const float*)d_in[6];
    const float* b2   = (const float*)d_in[7];
    const float* We1  = (const float*)d_in[8];
    const float* be1  = (const float*)d_in[9];
    const float* We2  = (const float*)d_in[10];
    const float* be2  = (const float*)d_in[11];
    const int* ei     = (const int*)d_in[12];
    const int* ein    = (const int*)d_in[13];
    const int* eib    = (const int*)d_in[14];
    const int* einb   = (const int*)d_in[15];
    const int* batch  = (const int*)d_in[16];

    const int N = in_sizes[0] / D;       // 100000
    const int E = in_sizes[14];          // 600000
    const int G = 1024;

    float* ws = (float*)d_ws;
    float* posSum = ws;                  // [G]
    float* negSum = ws + G;              // [G]
    float* klSum  = ws + 2 * G;          // [G]
    float* tot    = ws + 3 * G;          // [0]=loss, [1]=sum lep, [2]=sum len

    hipMemsetAsync(d_ws, 0, (size_t)(3 * G + 3) * sizeof(float), stream);

    const int ntiles = (E + 63) / 64;

    pos_kernel<<<512, 512, 0, stream>>>(x, ei, eib, W1, b1, W2, b2,
                                        We1, be1, We2, be2, attr,
                                        posSum, tot + 1, E, ntiles);
    neg_kernel<<<512, 512, 0, stream>>>(x, ein, einb, We1, be1, We2, be2,
                                        negSum, tot + 2, E, ntiles);
    kl_kernel<<<(N + 255) / 256, 256, 0, stream>>>(xm, xsd, batch, klSum, N);
    final_kernel<<<(G + 255) / 256, 256, 0, stream>>>(eib, einb, batch,
                                                      posSum, negSum, klSum, tot, E, N, G);
    out_kernel<<<1, 64, 0, stream>>>(tot, (float*)d_out, E, G);
}

// Round 5
// 668.291 us; speedup vs baseline: 5.9315x; 1.4591x over previous
//
#include <hip/hip_runtime.h>
#include <math.h>

#define D 128

typedef __bf16 bf16x8 __attribute__((ext_vector_type(8)));
typedef float f32x4 __attribute__((ext_vector_type(4)));

__device__ __forceinline__ unsigned short f2bf(float f) {
    unsigned u = __float_as_uint(f);
    return (unsigned short)((u + 0x7FFFu + ((u >> 16) & 1u)) >> 16);
}
__device__ __forceinline__ float bf2f(unsigned short h) {
    return __uint_as_float(((unsigned)h) << 16);
}

__device__ __forceinline__ int lbound(const int* __restrict__ a, int L, int v) {
    int lo = 0, hi = L;
    while (lo < hi) { int m = (lo + hi) >> 1; if (a[m] < v) lo = m + 1; else hi = m; }
    return lo;
}

// Wave-level segmented atomic accumulate; all 64 lanes of the wave converged.
__device__ __forceinline__ void seg_atomic(float* __restrict__ seg, int g, float v, bool valid) {
    float tv = valid ? v : 0.f;
    float s = tv;
#pragma unroll
    for (int o = 1; o < 64; o <<= 1) s += __shfl_xor(s, o, 64);
    unsigned long long vb = __ballot(valid);
    if (vb == 0ULL) return;
    int g0 = __shfl(g, __ffsll((unsigned long long)vb) - 1, 64);
    unsigned long long ub = __ballot((!valid) || (g == g0));
    const int lane = (int)(threadIdx.x & 63u);
    if (ub == ~0ULL) {
        if (lane == 0) atomicAdd(seg + g0, s);
    } else {
        if (valid) atomicAdd(seg + g, tv);
    }
}

__device__ __forceinline__ void wave_add(float* __restrict__ dst, float v) {
    float s = v;
#pragma unroll
    for (int o = 1; o < 64; o <<= 1) s += __shfl_xor(s, o, 64);
    if ((threadIdx.x & 63u) == 0) atomicAdd(dst, s);
}

// A-fragment LDS layout (16x16x32 MFMA): slot(mt,kt,quad,m) = ((mt*4+kt)*64 + quad*16 + m),
// 16 B per slot; reader lane l uses slot ((mt*4+kt)*64 + l) -> linear, conflict-free.

// Positive-edge kernel: both heads, M=64 edges/tile, 8 waves.
// Waves 0-3: W1-head cols 32w..32w+32 (plain bf16).  Waves 4-7: We1-head (hi+lo bf16).
// tot1 contribution accumulated in a REGISTER across tiles; ONE atomic per wave at
// kernel end (per-tile atomics to a single address + barrier vmcnt(0) drain was the
// R4 serializer: 37.5K same-address RMWs ~= 34 cyc each = the whole 528 us).
__global__ __launch_bounds__(512, 4)
void pos_kernel(const float* __restrict__ x,
                const int* __restrict__ ei, const int* __restrict__ ebatch,
                const float* __restrict__ W1, const float* __restrict__ b1,
                const float* __restrict__ W2, const float* __restrict__ b2,
                const float* __restrict__ We1, const float* __restrict__ be1,
                const float* __restrict__ We2, const float* __restrict__ be2,
                const float* __restrict__ attr,
                float* __restrict__ posSum, float* __restrict__ tot1,
                int E, int ntiles) {
    __shared__ float smem[9104];
    unsigned short* As  = (unsigned short*)smem;            // 1024 slots x 16 B (16 KB)
    unsigned short* Hbf = (unsigned short*)(smem + 4096);   // H1 relu'd: [64][136] bf16
    float* posP = smem + 8448;                              // [4][64] We-head partials
    float* b1s  = smem + 8704;
    float* be1s = smem + 8832;
    float* We2s = smem + 8960;
    float* b2s  = smem + 9088;                              // 7 (+1)
    float* be2s = smem + 9096;

    const int t   = (int)threadIdx.x;
    const int wv  = t >> 6;
    const int l   = t & 63;
    const int sub = l & 15;
    const int q   = l >> 4;

    bf16x8 Bh[2][4];   // wv<4: W1 cols; wv>=4: We1-hi cols
    bf16x8 Bl[2][4];   // wv>=4: We1-lo; wv<4: Bl[0][kt] = W2 fragment (layer-2 GEMM)

    // ---- one-time B staging: 12 passes through the A region
#pragma unroll
    for (int pass = 0; pass < 12; pass++) {
        const int mm = (pass < 4) ? 0 : 1;
        const int p  = (pass < 8) ? 0 : 1;
        const int kt = pass & 3;
        const float* Wsrc = mm ? We1 : W1;
        __syncthreads();
        {
            const int ct = t >> 6, ln = t & 63;
            const int n  = ct * 16 + (ln & 15);
            const int kb = kt * 32 + (ln >> 4) * 8;
            unsigned v[4];
#pragma unroll
            for (int jj = 0; jj < 4; jj++) {
                float f0 = Wsrc[(kb + 2 * jj) * D + n];
                float f1 = Wsrc[(kb + 2 * jj + 1) * D + n];
                unsigned short h0, h1;
                if (p == 0) { h0 = f2bf(f0); h1 = f2bf(f1); }
                else {
                    h0 = f2bf(f0 - bf2f(f2bf(f0)));
                    h1 = f2bf(f1 - bf2f(f2bf(f1)));
                }
                v[jj] = (unsigned)h0 | ((unsigned)h1 << 16);
            }
            uint4 u; u.x = v[0]; u.y = v[1]; u.z = v[2]; u.w = v[3];
            *(uint4*)(As + (ct * 64 + ln) * 8) = u;
        }
        __syncthreads();
        int ct0 = -1;
        if (mm == 0 && wv < 4)  ct0 = 2 * wv;
        if (mm == 1 && wv >= 4) ct0 = 2 * (wv - 4);
        if (ct0 >= 0) {
            bf16x8 f0 = *(const bf16x8*)(As + (ct0 * 64 + l) * 8);
            bf16x8 f1 = *(const bf16x8*)(As + ((ct0 + 1) * 64 + l) * 8);
            if (p == 0) { Bh[0][kt] = f0; Bh[1][kt] = f1; }
            else        { Bl[0][kt] = f0; Bl[1][kt] = f1; }
        }
    }
    // wv<4: W2 fragments (B-operand of the 64x16x128 layer-2 GEMM), cols 7..15 zero
    if (wv < 4) {
#pragma unroll
        for (int kt = 0; kt < 4; kt++) {
            const int kb = kt * 32 + q * 8;
            unsigned v[4];
#pragma unroll
            for (int jj = 0; jj < 4; jj++) {
                unsigned short h0 = (sub < 7) ? f2bf(W2[(kb + 2 * jj) * 7 + sub]) : (unsigned short)0;
                unsigned short h1 = (sub < 7) ? f2bf(W2[(kb + 2 * jj + 1) * 7 + sub]) : (unsigned short)0;
                v[jj] = (unsigned)h0 | ((unsigned)h1 << 16);
            }
            union { uint4 u; bf16x8 b; } cv;
            cv.u.x = v[0]; cv.u.y = v[1]; cv.u.z = v[2]; cv.u.w = v[3];
            Bl[0][kt] = cv.b;
        }
    }
    __syncthreads();
    if (t < 128) { b1s[t] = b1[t]; be1s[t] = be1[t]; We2s[t] = We2[t]; }
    if (t < 7) b2s[t] = b2[t];
    if (t == 7) be2s[0] = be2[0];
    __syncthreads();

    float lpAcc = 0.f;                      // per-lane running sum for tot1

    for (int tile = (int)blockIdx.x; tile < ntiles; tile += (int)gridDim.x) {
        const int base = tile * 64;
        // ---- gather em = relu(x[s]*x[d]) -> bf16 -> swizzled A frags
        // (no barrier needed here: As reads of prev tile ended before prev barrier-M,
        //  and layer-2 below only touches Hbf/posP, disjoint from As)
        {
            const int e = t >> 3, ks = t & 7;
            const int Ei = base + e, k0 = ks * 16;
            unsigned v[8];
            if (Ei < E) {
                const int s0 = ei[Ei], d0 = ei[E + Ei];
                const float4* ps = (const float4*)(x + (size_t)s0 * D + k0);
                const float4* pd = (const float4*)(x + (size_t)d0 * D + k0);
#pragma unroll
                for (int i2 = 0; i2 < 4; i2++) {
                    float4 a = ps[i2], b = pd[i2];
                    unsigned short p0 = f2bf(fmaxf(a.x * b.x, 0.f));
                    unsigned short p1 = f2bf(fmaxf(a.y * b.y, 0.f));
                    unsigned short p2 = f2bf(fmaxf(a.z * b.z, 0.f));
                    unsigned short p3 = f2bf(fmaxf(a.w * b.w, 0.f));
                    v[i2 * 2]     = (unsigned)p0 | ((unsigned)p1 << 16);
                    v[i2 * 2 + 1] = (unsigned)p2 | ((unsigned)p3 << 16);
                }
            } else {
#pragma unroll
                for (int i2 = 0; i2 < 8; i2++) v[i2] = 0u;
            }
            const int slot = ((e >> 4) * 4 + (ks >> 1)) * 64 + (ks & 1) * 32 + (e & 15);
            uint4 u0; u0.x = v[0]; u0.y = v[1]; u0.z = v[2]; u0.w = v[3];
            uint4 u1; u1.x = v[4]; u1.y = v[5]; u1.z = v[6]; u1.w = v[7];
            *(uint4*)(As + slot * 8) = u0;
            *(uint4*)(As + (slot + 16) * 8) = u1;
        }
        __syncthreads();                    // barrier G
        // ---- layer-1 MFMAs + per-wave epilogue
#pragma unroll
        for (int mt = 0; mt < 4; mt++) {
            bf16x8 a0 = *(const bf16x8*)(As + ((mt * 4 + 0) * 64 + l) * 8);
            bf16x8 a1 = *(const bf16x8*)(As + ((mt * 4 + 1) * 64 + l) * 8);
            bf16x8 a2 = *(const bf16x8*)(As + ((mt * 4 + 2) * 64 + l) * 8);
            bf16x8 a3 = *(const bf16x8*)(As + ((mt * 4 + 3) * 64 + l) * 8);
            float zp0 = 0.f, zp1 = 0.f, zp2 = 0.f, zp3 = 0.f;
#pragma unroll
            for (int ct = 0; ct < 2; ct++) {
                f32x4 c = {0.f, 0.f, 0.f, 0.f};
                c = __builtin_amdgcn_mfma_f32_16x16x32_bf16(a0, Bh[ct][0], c, 0, 0, 0);
                c = __builtin_amdgcn_mfma_f32_16x16x32_bf16(a1, Bh[ct][1], c, 0, 0, 0);
                c = __builtin_amdgcn_mfma_f32_16x16x32_bf16(a2, Bh[ct][2], c, 0, 0, 0);
                c = __builtin_amdgcn_mfma_f32_16x16x32_bf16(a3, Bh[ct][3], c, 0, 0, 0);
                if (wv >= 4) {
                    c = __builtin_amdgcn_mfma_f32_16x16x32_bf16(a0, Bl[ct][0], c, 0, 0, 0);
                    c = __builtin_amdgcn_mfma_f32_16x16x32_bf16(a1, Bl[ct][1], c, 0, 0, 0);
                    c = __builtin_amdgcn_mfma_f32_16x16x32_bf16(a2, Bl[ct][2], c, 0, 0, 0);
                    c = __builtin_amdgcn_mfma_f32_16x16x32_bf16(a3, Bl[ct][3], c, 0, 0, 0);
                }
                const int jloc = (wv & 3) * 32 + ct * 16 + sub;
                if (wv < 4) {
                    const float bb = b1s[jloc];
#pragma unroll
                    for (int r = 0; r < 4; r++)
                        Hbf[(mt * 16 + q * 4 + r) * 136 + jloc] = f2bf(fmaxf(c[r] + bb, 0.f));
                } else {
                    const float bb = be1s[jloc], ww = We2s[jloc];
                    zp0 += fmaxf(c[0] + bb, 0.f) * ww;
                    zp1 += fmaxf(c[1] + bb, 0.f) * ww;
                    zp2 += fmaxf(c[2] + bb, 0.f) * ww;
                    zp3 += fmaxf(c[3] + bb, 0.f) * ww;
                }
            }
            if (wv >= 4) {
#pragma unroll
                for (int o = 1; o < 16; o <<= 1) {
                    zp0 += __shfl_xor(zp0, o, 64);
                    zp1 += __shfl_xor(zp1, o, 64);
                    zp2 += __shfl_xor(zp2, o, 64);
                    zp3 += __shfl_xor(zp3, o, 64);
                }
                if (sub < 4) {
                    float vv = (sub == 0) ? zp0 : (sub == 1) ? zp1 : (sub == 2) ? zp2 : zp3;
                    posP[(wv - 4) * 64 + mt * 16 + q * 4 + sub] = vv;
                }
            }
        }
        __syncthreads();                    // barrier M
        // ---- layer 2 (waves 0-3): S = Hbf @ W2frag via MFMA; lane sub==7 does We-head
        if (wv < 4) {
            f32x4 cS = {0.f, 0.f, 0.f, 0.f};
#pragma unroll
            for (int jt = 0; jt < 4; jt++) {
                bf16x8 hf = *(const bf16x8*)(Hbf + (wv * 16 + sub) * 136 + jt * 32 + q * 8);
                cS = __builtin_amdgcn_mfma_f32_16x16x32_bf16(hf, Bl[0][jt], cS, 0, 0, 0);
            }
            float bceP[4] = {0.f, 0.f, 0.f, 0.f};
            float lpP[4]  = {0.f, 0.f, 0.f, 0.f};
#pragma unroll
            for (int r = 0; r < 4; r++) {
                const int e = wv * 16 + q * 4 + r;
                const int Ei = base + e;
                const bool vE = (Ei < E);
                if (sub < 7 && vE) {
                    const float z = cS[r] + b2s[sub];
                    const float p = 1.f / (1.f + expf(-z));
                    const float ta = attr[(size_t)Ei * 9 + sub];
                    bceP[r] = -(ta * fmaxf(logf(p), -100.f)
                              + (1.f - ta) * fmaxf(log1pf(-p), -100.f));
                } else if (sub == 7 && vE) {
                    const float zp = posP[e] + posP[64 + e] + posP[128 + e] + posP[192 + e] + be2s[0];
                    const float pp = 1.f / (1.f + expf(-zp));
                    lpP[r]  = -fmaxf(logf(pp), -100.f);
                    bceP[r] = lpP[r];
                }
            }
#pragma unroll
            for (int o = 1; o < 16; o <<= 1)
#pragma unroll
                for (int r = 0; r < 4; r++) {
                    bceP[r] += __shfl_xor(bceP[r], o, 64);
                    lpP[r]  += __shfl_xor(lpP[r],  o, 64);
                }
            const float lossSel = (sub == 0) ? bceP[0] : (sub == 1) ? bceP[1]
                                : (sub == 2) ? bceP[2] : bceP[3];
            const float lpSel   = (sub == 0) ? lpP[0] : (sub == 1) ? lpP[1]
                                : (sub == 2) ? lpP[2] : lpP[3];
            const int eW  = wv * 16 + q * 4 + (sub & 3);
            const int EiW = base + eW;
            const bool act = (sub < 4) && (EiW < E);
            const int g = ebatch[EiW < E ? EiW : E - 1];
            seg_atomic(posSum, g, lossSel, act);
            lpAcc += act ? lpSel : 0.f;     // register accumulate; atomic deferred
        }
    }
    if (wv < 4) wave_add(tot1, lpAcc);      // one atomic per wave per kernel
}

// Negative-edge kernel: We-head only. M=64, 8 waves x 16 cols, We1 hi+lo.
__global__ __launch_bounds__(512, 4)
void neg_kernel(const float* __restrict__ x,
                const int* __restrict__ ei, const int* __restrict__ ebatch,
                const float* __restrict__ We1, const float* __restrict__ be1,
                const float* __restrict__ We2, const float* __restrict__ be2,
                float* __restrict__ negSum, float* __restrict__ tot2,
                int E, int ntiles) {
    __shared__ float smem[4872];
    unsigned short* As = (unsigned short*)smem;     // 16 KB A frags
    float* negP = smem + 4096;                      // [8][64]
    float* be1s = smem + 4608;
    float* We2s = smem + 4736;
    float* be2s = smem + 4864;

    const int t   = (int)threadIdx.x;
    const int wv  = t >> 6;
    const int l   = t & 63;
    const int sub = l & 15;
    const int q   = l >> 4;

    bf16x8 Bh[4], Bl[4];
#pragma unroll
    for (int pass = 0; pass < 8; pass++) {
        const int p  = pass >> 2;
        const int kt = pass & 3;
        __syncthreads();
        {
            const int ct = t >> 6, ln = t & 63;
            const int n  = ct * 16 + (ln & 15);
            const int kb = kt * 32 + (ln >> 4) * 8;
            unsigned v[4];
#pragma unroll
            for (int jj = 0; jj < 4; jj++) {
                float f0 = We1[(kb + 2 * jj) * D + n];
                float f1 = We1[(kb + 2 * jj + 1) * D + n];
                unsigned short h0, h1;
                if (p == 0) { h0 = f2bf(f0); h1 = f2bf(f1); }
                else {
                    h0 = f2bf(f0 - bf2f(f2bf(f0)));
                    h1 = f2bf(f1 - bf2f(f2bf(f1)));
                }
                v[jj] = (unsigned)h0 | ((unsigned)h1 << 16);
            }
            uint4 u; u.x = v[0]; u.y = v[1]; u.z = v[2]; u.w = v[3];
            *(uint4*)(As + (ct * 64 + ln) * 8) = u;
        }
        __syncthreads();
        {
            bf16x8 f0 = *(const bf16x8*)(As + (wv * 64 + l) * 8);
            if (p == 0) Bh[kt] = f0; else Bl[kt] = f0;
        }
    }
    __syncthreads();
    if (t < 128) { be1s[t] = be1[t]; We2s[t] = We2[t]; }
    if (t == 128) be2s[0] = be2[0];
    __syncthreads();

    float lnAcc = 0.f;

    for (int tile = (int)blockIdx.x; tile < ntiles; tile += (int)gridDim.x) {
        const int base = tile * 64;
        {
            const int e = t >> 3, ks = t & 7;
            const int Ei = base + e, k0 = ks * 16;
            unsigned v[8];
            if (Ei < E) {
                const int s0 = ei[Ei], d0 = ei[E + Ei];
                const float4* ps = (const float4*)(x + (size_t)s0 * D + k0);
                const float4* pd = (const float4*)(x + (size_t)d0 * D + k0);
#pragma unroll
                for (int i2 = 0; i2 < 4; i2++) {
                    float4 a = ps[i2], b = pd[i2];
                    unsigned short p0 = f2bf(fmaxf(a.x * b.x, 0.f));
                    unsigned short p1 = f2bf(fmaxf(a.y * b.y, 0.f));
                    unsigned short p2 = f2bf(fmaxf(a.z * b.z, 0.f));
                    unsigned short p3 = f2bf(fmaxf(a.w * b.w, 0.f));
                    v[i2 * 2]     = (unsigned)p0 | ((unsigned)p1 << 16);
                    v[i2 * 2 + 1] = (unsigned)p2 | ((unsigned)p3 << 16);
                }
            } else {
#pragma unroll
                for (int i2 = 0; i2 < 8; i2++) v[i2] = 0u;
            }
            const int slot = ((e >> 4) * 4 + (ks >> 1)) * 64 + (ks & 1) * 32 + (e & 15);
            uint4 u0; u0.x = v[0]; u0.y = v[1]; u0.z = v[2]; u0.w = v[3];
            uint4 u1; u1.x = v[4]; u1.y = v[5]; u1.z = v[6]; u1.w = v[7];
            *(uint4*)(As + slot * 8) = u0;
            *(uint4*)(As + (slot + 16) * 8) = u1;
        }
        __syncthreads();
        const int j = wv * 16 + sub;
        const float bb = be1s[j], ww = We2s[j];
#pragma unroll
        for (int mt = 0; mt < 4; mt++) {
            bf16x8 a0 = *(const bf16x8*)(As + ((mt * 4 + 0) * 64 + l) * 8);
            bf16x8 a1 = *(const bf16x8*)(As + ((mt * 4 + 1) * 64 + l) * 8);
            bf16x8 a2 = *(const bf16x8*)(As + ((mt * 4 + 2) * 64 + l) * 8);
            bf16x8 a3 = *(const bf16x8*)(As + ((mt * 4 + 3) * 64 + l) * 8);
            f32x4 c = {0.f, 0.f, 0.f, 0.f};
            c = __builtin_amdgcn_mfma_f32_16x16x32_bf16(a0, Bh[0], c, 0, 0, 0);
            c = __builtin_amdgcn_mfma_f32_16x16x32_bf16(a1, Bh[1], c, 0, 0, 0);
            c = __builtin_amdgcn_mfma_f32_16x16x32_bf16(a2, Bh[2], c, 0, 0, 0);
            c = __builtin_amdgcn_mfma_f32_16x16x32_bf16(a3, Bh[3], c, 0, 0, 0);
            c = __builtin_amdgcn_mfma_f32_16x16x32_bf16(a0, Bl[0], c, 0, 0, 0);
            c = __builtin_amdgcn_mfma_f32_16x16x32_bf16(a1, Bl[1], c, 0, 0, 0);
            c = __builtin_amdgcn_mfma_f32_16x16x32_bf16(a2, Bl[2], c, 0, 0, 0);
            c = __builtin_amdgcn_mfma_f32_16x16x32_bf16(a3, Bl[3], c, 0, 0, 0);
            float zp0 = fmaxf(c[0] + bb, 0.f) * ww;
            float zp1 = fmaxf(c[1] + bb, 0.f) * ww;
            float zp2 = fmaxf(c[2] + bb, 0.f) * ww;
            float zp3 = fmaxf(c[3] + bb, 0.f) * ww;
#pragma unroll
            for (int o = 1; o < 16; o <<= 1) {
                zp0 += __shfl_xor(zp0, o, 64);
                zp1 += __shfl_xor(zp1, o, 64);
                zp2 += __shfl_xor(zp2, o, 64);
                zp3 += __shfl_xor(zp3, o, 64);
            }
            if (sub < 4) {
                float vv = (sub == 0) ? zp0 : (sub == 1) ? zp1 : (sub == 2) ? zp2 : zp3;
                negP[wv * 64 + mt * 16 + q * 4 + sub] = vv;
            }
        }
        __syncthreads();
        if (wv == 0) {
            const int Ei = base + l;
            const bool valid = (Ei < E);
            float zp = be2s[0];
#pragma unroll
            for (int i = 0; i < 8; i++) zp += negP[i * 64 + l];
            float lossN = 0.f;
            if (valid) {
                const float pp = 1.f / (1.f + expf(-zp));
                lossN = -fmaxf(log1pf(-pp), -100.f);
            }
            const int g = ebatch[Ei < E ? Ei : E - 1];
            seg_atomic(negSum, g, lossN, valid);
            lnAcc += valid ? lossN : 0.f;
        }
    }
    if (wv == 0) wave_add(tot2, lnAcc);
}

__global__ __launch_bounds__(256)
void kl_kernel(const float* __restrict__ xm, const float* __restrict__ xs,
               const int* __restrict__ batch, float* __restrict__ klSum, int N) {
    const int n = (int)(blockIdx.x * 256 + threadIdx.x);
    const bool valid = (n < N);
    float kl = 0.f;
    int g = 0;
    if (valid) {
        const float4* m4 = (const float4*)(xm + (size_t)n * D);
        const float4* s4 = (const float4*)(xs + (size_t)n * D);
        float s = 0.f;
        // Clamp log at -1e4 (< log(min denormal)): bit-identical for sd > 0,
        // finite at sd == 0 where the reference is +inf (threshold inf).
#pragma unroll 8
        for (int i = 0; i < 32; i++) {
            const float4 m = m4[i];
            const float4 sd = s4[i];
            s += 1.f + 2.f * fmaxf(logf(sd.x), -1e4f) - m.x * m.x - sd.x * sd.x;
            s += 1.f + 2.f * fmaxf(logf(sd.y), -1e4f) - m.y * m.y - sd.y * sd.y;
            s += 1.f + 2.f * fmaxf(logf(sd.z), -1e4f) - m.z * m.z - sd.z * sd.z;
            s += 1.f + 2.f * fmaxf(logf(sd.w), -1e4f) - m.w * m.w - sd.w * sd.w;
        }
        kl = -0.5f * s;
        g = batch[n];
    }
    seg_atomic(klSum, g, kl, valid);
}

__global__ __launch_bounds__(256)
void final_kernel(const int* __restrict__ eib, const int* __restrict__ einb,
                  const int* __restrict__ nbatch,
                  const float* __restrict__ posSum, const float* __restrict__ negSum,
                  const float* __restrict__ klSum,
                  float* __restrict__ tot, int E, int N, int G) {
    const int g = (int)(blockIdx.x * blockDim.x + threadIdx.x);
    float lg = 0.f;
    if (g < G) {
        const int cP = lbound(eib, E, g + 1) - lbound(eib, E, g);
        const int cN = lbound(einb, E, g + 1) - lbound(einb, E, g);
        const int cB = lbound(nbatch, N, g + 1) - lbound(nbatch, N, g);
        const float fp = fmaxf((float)cP, 1.f);
        const float fn = fmaxf((float)cN, 1.f);
        const float fb = fmaxf((float)cB, 1.f);
        lg = posSum[g] / fp + negSum[g] / fn + (klSum[g] / fb) / fb;
    }
#pragma unroll
    for (int o = 1; o < 64; o <<= 1) lg += __shfl_xor(lg, o, 64);
    if ((threadIdx.x & 63u) == 0) atomicAdd(tot, lg);
}

__global__ void out_kernel(const float* __restrict__ tot, float* __restrict__ out,
                           int E, int G) {
    if (threadIdx.x == 0 && blockIdx.x == 0) {
        out[0] = tot[0] / (float)G;
        out[1] = 0.5f * (tot[1] / (float)E + tot[2] / (float)E);
    }
}

extern "C" void kernel_launch(void* const* d_in, const int* in_sizes, int n_in,
                              void* d_out, int out_size, void* d_ws, size_t ws_size,
                              hipStream_t stream) {
    const float* x    = (const float*)d_in[0];
    const float* attr = (const float*)d_in[1];
    const float* xm   = (const float*)d_in[2];
    const float* xsd  = (const float*)d_in[3];
    const float* W1   = (const float*)d_in[4];
    const float* b1   = (const float*)d_in[5];
    const float* W2   = (const float*)d_in[6];
    const float* b2   = (const float*)d_in[7];
    const float* We1  = (const float*)d_in[8];
    const float* be1  = (const float*)d_in[9];
    const float* We2  = (const float*)d_in[10];
    const float* be2  = (const float*)d_in[11];
    const int* ei     = (const int*)d_in[12];
    const int* ein    = (const int*)d_in[13];
    const int* eib    = (const int*)d_in[14];
    const int* einb   = (const int*)d_in[15];
    const int* batch  = (const int*)d_in[16];

    const int N = in_sizes[0] / D;       // 100000
    const int E = in_sizes[14];          // 600000
    const int G = 1024;

    float* ws = (float*)d_ws;
    float* posSum = ws;                  // [G]
    float* negSum = ws + G;              // [G]
    float* klSum  = ws + 2 * G;          // [G]
    float* tot    = ws + 3 * G;          // [0]=loss, [1]=sum lep, [2]=sum len

    hipMemsetAsync(d_ws, 0, (size_t)(3 * G + 3) * sizeof(float), stream);

    const int ntiles = (E + 63) / 64;
    const int grid = ntiles < 1024 ? ntiles : 1024;   // 4 blocks/CU

    pos_kernel<<<grid, 512, 0, stream>>>(x, ei, eib, W1, b1, W2, b2,
                                         We1, be1, We2, be2, attr,
                                         posSum, tot + 1, E, ntiles);
    neg_kernel<<<grid, 512, 0, stream>>>(x, ein, einb, We1, be1, We2, be2,
                                         negSum, tot + 2, E, ntiles);
    kl_kernel<<<(N + 255) / 256, 256, 0, stream>>>(xm, xsd, batch, klSum, N);
    final_kernel<<<(G + 255) / 256, 256, 0, stream>>>(eib, einb, batch,
                                                      posSum, negSum, klSum, tot, E, N, G);
    out_kernel<<<1, 64, 0, stream>>>(tot, (float*)d_out, E, G);
}